// Round 3
// baseline (354.282 us; speedup 1.0000x reference)
//
#include <hip/hip_runtime.h>

#define K2D 26400
#define NFB 1024
#define NBT 80
#define MAXN 13
#define MTOT (NBT * MAXN)   // 1040
#define NA 6
#define NG 5
#define KITERS 825          // K2D / 32
#define TILEB 8192          // bytes of one packed 128x32 bf16 tile image
#define AIMG 10             // A pack images of 128 rows (covers 1280 >= 1040)
#define NT128 8             // B pack images (128 cols each)
#define MT256 5             // GEMM M tiles of 256
#define NT256 4             // GEMM N tiles of 256
#define ITS 5               // A-pack k-iters per block (640-B row segments)
#define ITG (KITERS / ITS)  // 165

typedef __attribute__((ext_vector_type(8))) short     bf16x8;
typedef __attribute__((ext_vector_type(4))) float     f32x4;
typedef __attribute__((ext_vector_type(4))) unsigned short us4;
typedef __attribute__((ext_vector_type(8))) unsigned short us8;

__device__ __forceinline__ unsigned short f2bf(float x) {
    unsigned u = __float_as_uint(x);
    u += 0x7fffu + ((u >> 16) & 1u);
    return (unsigned short)(u >> 16);
}

__device__ __forceinline__ void gload_lds16(const void* g, void* l) {
    __builtin_amdgcn_global_load_lds(
        (const __attribute__((address_space(1))) unsigned int*)g,
        (__attribute__((address_space(3))) unsigned int*)l, 16, 0, 0);
}

// meta layout (ints): [0]=total, [1..81]=offsets[0..80], [82..82+1039]=row map
#define META_OFFS 1
#define META_MAP  82

// ---- parallel prefix of box counts + compacted-row -> source-row map
__global__ __launch_bounds__(256) void prefix_kernel(const int* __restrict__ nb,
                                                     int* __restrict__ meta)
{
    __shared__ int a[128];
    const int t = threadIdx.x;
    if (t < 128) a[t] = (t < NBT) ? nb[t] : 0;
    __syncthreads();
#pragma unroll
    for (int s = 1; s < 128; s <<= 1) {       // Hillis-Steele inclusive scan
        int v = 0;
        if (t < 128 && t >= s) v = a[t - s];
        __syncthreads();
        if (t < 128) a[t] += v;
        __syncthreads();
    }
    if (t == 0) { meta[0] = a[NBT - 1]; meta[META_OFFS] = 0; }
    if (t < NBT) meta[META_OFFS + t + 1] = a[t];
    for (int f = t; f < NBT * MAXN; f += 256) {
        const int bt = f / MAXN, n = f % MAXN;
        const int o0 = bt ? a[bt - 1] : 0;
        if (n < a[bt] - o0) meta[META_MAP + o0 + n] = f;
    }
}

// ---- fused pack v3, LDS-FREE (concurrency-optimized):
//   R1 (8KB LDS, 71% occ) and R2 (40KB LDS, 34% occ) both pinned at 2.0 TB/s
//   -> limiter is waves x bytes-in-flight, throttled by the load->cvt->store
//   vmcnt drain and the LDS block allocation. v3: zero LDS (A path stores
//   converted us4 directly -- per wave the stores form 4x128-B contiguous
//   runs), B path manually 2-deep (16 loads / 64 B per thread in flight).
//   Image byte layout unchanged -> GEMM untouched.
__global__ __launch_bounds__(256, 4) void pack_ab(
    const float* __restrict__ A, const float* __restrict__ W,
    const int* __restrict__ meta,
    unsigned short* __restrict__ Aout, unsigned short* __restrict__ Bout)
{
    const int id = blockIdx.x, t = threadIdx.x;

    if (id < KITERS) {                       // ---- B (weights) path
        const int it = id;
        const float* wbase = W + (size_t)it * 32 * NFB;   // 32 whole rows
        unsigned short* ob = Bout + (size_t)it * (TILEB / 2);
#pragma unroll
        for (int cp = 0; cp < 8; ++cp) {
            const int c0 = (2 * cp) * 256 + t;   // c = bn*512 + q*128 + n
            const int c1 = c0 + 256;
            const int bn0 = c0 >> 9, q0 = (c0 >> 7) & 3, n0 = c0 & 127;
            const int bn1 = c1 >> 9, q1 = (c1 >> 7) & 3, n1 = c1 & 127;
            const float* bp0 = wbase + (size_t)(q0 * 8) * NFB + bn0 * 128 + n0;
            const float* bp1 = wbase + (size_t)(q1 * 8) * NFB + bn1 * 128 + n1;
            float v0[8], v1[8];
#pragma unroll
            for (int j = 0; j < 8; ++j) v0[j] = bp0[(size_t)j * NFB];
#pragma unroll
            for (int j = 0; j < 8; ++j) v1[j] = bp1[(size_t)j * NFB];
            us8 u0, u1;
#pragma unroll
            for (int j = 0; j < 8; ++j) u0[j] = f2bf(v0[j]);
#pragma unroll
            for (int j = 0; j < 8; ++j) u1[j] = f2bf(v1[j]);
            *(us8*)(ob + (size_t)bn0 * KITERS * (TILEB / 2) + (q0 * 128 + n0) * 8) = u0;
            *(us8*)(ob + (size_t)bn1 * KITERS * (TILEB / 2) + (q1 * 128 + n1) * 8) = u1;
        }
        return;
    }

    // ---- A (box features) path: gather rows, convert, store direct to image
    const int id2 = id - KITERS;
    const int bm  = id2 / ITG;
    const int itg = id2 % ITG;
    const int total = meta[0];
    if (bm * 128 >= total) return;   // untouched images only feed rows >= total
    const int it0 = itg * ITS;
#pragma unroll
    for (int i = 0; i < 4; ++i) {
        const int f  = t + i * 256;
        const int m  = f >> 3;
        const int kp = (f & 7) * 4;
        const int p  = bm * 128 + m;
        const int src = (p < total) ? meta[META_MAP + p] : 0;
        const float* ap = A + (size_t)src * K2D + it0 * 32 + kp;
        unsigned short* ob = Aout + (size_t)(bm * KITERS + it0) * (TILEB / 2)
                           + (kp >> 3) * 1024 + m * 8 + (kp & 7);
        float4 v[ITS];
#pragma unroll
        for (int j = 0; j < ITS; ++j) {
            float4 w = {0.f, 0.f, 0.f, 0.f};
            if (p < total) w = *(const float4*)(ap + j * 32);
            v[j] = w;
        }
#pragma unroll
        for (int j = 0; j < ITS; ++j) {
            us4 u = { f2bf(v[j].x), f2bf(v[j].y), f2bf(v[j].z), f2bf(v[j].w) };
            *(us4*)(ob + (size_t)j * (TILEB / 2)) = u;
        }
    }
}

// ---- pipelined 256x256 GEMM, 512 thr (8 waves of 64x128), 3 LDS stages.
//      4 load-instrs/wave per tile-issue -> s_waitcnt vmcnt(4) retires 1 tile.
//      1-D grid with XCD-group swizzle: the 4 bn-blocks sharing one A-stripe
//      sit at id-stride 8 -> same XCD (id%8 round-robin) -> A-stripe (688 KB)
//      + their 4 B-stripes (2.75 MB) fit the 4 MB per-XCD L2. Pair order is
//      bm-major so active blocks (low bm) still dispatch first.
__global__ __launch_bounds__(512, 2) void gemm_pipe(
    const unsigned short* __restrict__ Apack,
    const unsigned short* __restrict__ Bpack,
    float* __restrict__ Cp,
    const int* __restrict__ meta, int kchunk)
{
    __shared__ __attribute__((aligned(16))) unsigned short buf[3][4][4][128][8]; // 96 KB

    const int id     = (int)blockIdx.x;
    const int npairs = (int)(gridDim.x >> 2);        // MT256 * nchunks
    const int nmain  = npairs & ~7;
    int pair, bn;
    if (id < (nmain << 2)) { pair = ((id >> 5) << 3) + (id & 7); bn = (id >> 3) & 3; }
    else { const int r = id - (nmain << 2); pair = nmain + (r >> 2); bn = r & 3; }
    const int nch = npairs / MT256;
    const int bm  = pair / nch;                      // bm-major: active first
    const int s   = pair % nch;

    const int total = meta[0];
    if (bm * 256 >= total) return;

    const int t = threadIdx.x;
    const int wave = t >> 6, lane = t & 63;
    const int quad = lane >> 4, l16 = lane & 15;
    const int wmq = wave & 3;            // row quadrant (64 rows each)
    const int asel = wmq >> 1;           // A image 0/1
    const int wm128 = (wmq & 1) * 64;    // row base within A image
    const int bsel = wave >> 2;          // B image 0/1 (128 cols each)
    const int it0 = s * kchunk;
    const int it1 = min(KITERS, it0 + kchunk);   // kchunk%3==0, 825%3==0

    f32x4 acc[4][8] = {};

    {
        const int itlast = it1 - 1;
        const char* A0 = (const char*)Apack + (size_t)(2 * bm) * KITERS * TILEB;
        const char* A1 = (const char*)Apack + (size_t)(2 * bm + 1) * KITERS * TILEB;
        const char* B0 = (const char*)Bpack + (size_t)(2 * bn) * KITERS * TILEB;
        const char* B1 = (const char*)Bpack + (size_t)(2 * bn + 1) * KITERS * TILEB;
        const int go = t * 16;            // byte offset within an 8 KB image
        const int lo = wave * 1024;       // wave-uniform LDS base within image

#define ISSUE(IT, ST) do {                                                     \
    const size_t o_ = (size_t)(IT) * TILEB;                                    \
    gload_lds16(A0 + o_ + go, (char*)&buf[ST][0] + lo);                        \
    gload_lds16(A1 + o_ + go, (char*)&buf[ST][1] + lo);                        \
    gload_lds16(B0 + o_ + go, (char*)&buf[ST][2] + lo);                        \
    gload_lds16(B1 + o_ + go, (char*)&buf[ST][3] + lo);                        \
} while (0)

        ISSUE(it0, 0);
        { const int itp = min(it0 + 1, itlast); ISSUE(itp, 1); }

#define STEP(ITV, CUR, DST) do {                                               \
    asm volatile("" ::: "memory");                                             \
    __builtin_amdgcn_s_waitcnt(0xF74); /* vmcnt(4) */                          \
    __builtin_amdgcn_s_barrier();                                              \
    asm volatile("" ::: "memory");                                             \
    int itn = (ITV) + 2; itn = itn > itlast ? itlast : itn;                    \
    ISSUE(itn, DST);                                                           \
    bf16x8 af[4], bfr[8];                                                      \
    _Pragma("unroll")                                                          \
    for (int x = 0; x < 4; ++x)                                                \
        af[x] = *(const bf16x8*)(&buf[CUR][asel][quad][wm128 + x * 16 + l16][0]); \
    _Pragma("unroll")                                                          \
    for (int y = 0; y < 8; ++y)                                                \
        bfr[y] = *(const bf16x8*)(&buf[CUR][2 + bsel][quad][y * 16 + l16][0]); \
    _Pragma("unroll")                                                          \
    for (int x = 0; x < 4; ++x)                                                \
        _Pragma("unroll")                                                      \
        for (int y = 0; y < 8; ++y)                                            \
            acc[x][y] = __builtin_amdgcn_mfma_f32_16x16x32_bf16(               \
                af[x], bfr[y], acc[x][y], 0, 0, 0);                            \
} while (0)

        for (int it = it0; it < it1; it += 3) {
            STEP(it,     0, 2);
            STEP(it + 1, 1, 0);
            STEP(it + 2, 2, 1);
        }
#undef STEP
#undef ISSUE
    }

    // C write; rows >= total are garbage but never read downstream.
#pragma unroll
    for (int x = 0; x < 4; ++x) {
        const int rowb = bm * 256 + wmq * 64 + x * 16 + quad * 4;
#pragma unroll
        for (int y = 0; y < 8; ++y) {
            const int col = bn * 256 + bsel * 128 + y * 16 + l16;
#pragma unroll
            for (int r = 0; r < 4; ++r) {
                const int rr = rowb + r;
                if (rr < MTOT)
                    Cp[((size_t)s * MTOT + rr) * NFB + col] = acc[x][y][r];
            }
        }
    }
}

// ---- parallel split-K reduce: one block per compacted row
__global__ __launch_bounds__(256) void reduce_kernel(
    const float* __restrict__ Cp, const float* __restrict__ b_emb,
    float* __restrict__ h, const int* __restrict__ meta, int splitk)
{
    const int row = blockIdx.x;
    if (row >= meta[0]) return;
    const int t = threadIdx.x;
    const size_t base = (size_t)row * NFB + t * 4;
    float4 v = *(const float4*)(Cp + base);
#pragma unroll 4
    for (int s2 = 1; s2 < splitk; ++s2) {
        const float4 w = *(const float4*)(Cp + (size_t)s2 * MTOT * NFB + base);
        v.x += w.x; v.y += w.y; v.z += w.z; v.w += w.w;
    }
    const float4 be = *(const float4*)(b_emb + t * 4);
    v.x = fmaxf(v.x + be.x, 0.f);
    v.y = fmaxf(v.y + be.y, 0.f);
    v.z = fmaxf(v.z + be.z, 0.f);
    v.w = fmaxf(v.w + be.w, 0.f);
    *(float4*)(h + base) = v;
}

// ---- per-frame heads on compacted h
__global__ __launch_bounds__(256) void heads_kernel(
    const float* __restrict__ h,
    const float* __restrict__ w_act,  const float* __restrict__ b_act,
    const float* __restrict__ w_acty, const float* __restrict__ b_acty,
    const int* __restrict__ meta, float* __restrict__ out)
{
    __shared__ __attribute__((aligned(16))) float hs[MAXN][NFB];
    __shared__ float pooled[NFB];
    const int bt = blockIdx.x;
    const int t  = threadIdx.x;
    const int off0 = meta[META_OFFS + bt];
    const int Nb   = meta[META_OFFS + bt + 1] - off0;

    for (int i = 0; i < MAXN; ++i)
        if (i < Nb)
            *(float4*)(&hs[i][t * 4]) =
                *(const float4*)(h + (size_t)(off0 + i) * NFB + t * 4);
    __syncthreads();

    const int wave = t >> 6, lane = t & 63;

    for (int d = wave; d < MAXN * NA; d += 4) {
        const int n = d / NA, a = d % NA;
        if (n < Nb) {
            float sum = 0.f;
            for (int f = lane; f < NFB; f += 64)
                sum += hs[n][f] * w_act[f * NA + a];
#pragma unroll
            for (int o = 32; o > 0; o >>= 1) sum += __shfl_xor(sum, o);
            if (lane == 0) out[bt * (MAXN * NA) + d] = sum + b_act[a];
        } else {
            if (lane == 0) out[bt * (MAXN * NA) + d] = 0.f;
        }
    }

    for (int f = t; f < NFB; f += 256) {
        float m = hs[0][f];
        for (int n2 = 1; n2 < Nb; ++n2) m = fmaxf(m, hs[n2][f]);
        pooled[f] = m;
    }
    __syncthreads();

    for (int g = wave; g < NG; g += 4) {
        float sum = 0.f;
        for (int f = lane; f < NFB; f += 64)
            sum += pooled[f] * w_acty[f * NG + g];
#pragma unroll
        for (int o = 32; o > 0; o >>= 1) sum += __shfl_xor(sum, o);
        if (lane == 0)
            out[NBT * MAXN * NA + bt * NG + g] = sum + b_acty[g];
    }
}

// ======== fallback path (round-1 proven), used only if ws too small ========
__global__ __launch_bounds__(256) void gemm_f32(
    const float* __restrict__ A, const float* __restrict__ B,
    float* __restrict__ Cp, int kchunk)
{
    __shared__ __attribute__((aligned(16))) unsigned short Alds[4][128][8];
    __shared__ __attribute__((aligned(16))) unsigned short Blds[4][128][8];
    const int t = threadIdx.x;
    const int bm = blockIdx.x, bn = blockIdx.y, s = blockIdx.z;
    const int wave = t >> 6, lane = t & 63;
    const int quad = lane >> 4, l16 = lane & 15;
    const int wm = (wave & 1) * 64, wn = (wave >> 1) * 64;
    const int row0 = bm * 128, col0 = bn * 128;
    const int it0 = s * kchunk, it1 = min(KITERS, it0 + kchunk);

    f32x4 acc[4][4] = {};
    for (int it = it0; it < it1; ++it) {
        const int k0 = it * 32;
#pragma unroll
        for (int i = 0; i < 4; ++i) {
            const int f = t + i * 256, m = f >> 3, kp = (f & 7) * 4;
            const int gr = row0 + m;
            float4 v = {0.f, 0.f, 0.f, 0.f};
            if (gr < MTOT) v = *(const float4*)(A + (size_t)gr * K2D + k0 + kp);
            us4 u = { f2bf(v.x), f2bf(v.y), f2bf(v.z), f2bf(v.w) };
            *(us4*)(&Alds[kp >> 3][m][kp & 7]) = u;
        }
#pragma unroll
        for (int i = 0; i < 2; ++i) {
            const int p = t + i * 256, n = p & 127, kq = p >> 7;
            const float* bp = B + (size_t)(k0 + kq * 8) * NFB + (col0 + n);
            us8 u;
#pragma unroll
            for (int j = 0; j < 8; ++j) u[j] = f2bf(bp[(size_t)j * NFB]);
            *(us8*)(&Blds[kq][n][0]) = u;
        }
        __syncthreads();
        bf16x8 af[4], bfr[4];
#pragma unroll
        for (int x = 0; x < 4; ++x) {
            af[x]  = *(const bf16x8*)(&Alds[quad][wm + x * 16 + l16][0]);
            bfr[x] = *(const bf16x8*)(&Blds[quad][wn + x * 16 + l16][0]);
        }
#pragma unroll
        for (int x = 0; x < 4; ++x)
#pragma unroll
            for (int y = 0; y < 4; ++y)
                acc[x][y] = __builtin_amdgcn_mfma_f32_16x16x32_bf16(
                    af[x], bfr[y], acc[x][y], 0, 0, 0);
        __syncthreads();
    }
#pragma unroll
    for (int x = 0; x < 4; ++x) {
        const int rowb = row0 + wm + x * 16 + quad * 4;
#pragma unroll
        for (int y = 0; y < 4; ++y) {
            const int col = col0 + wn + y * 16 + l16;
#pragma unroll
            for (int r = 0; r < 4; ++r) {
                const int rr = rowb + r;
                if (rr < MTOT)
                    Cp[((size_t)s * MTOT + rr) * NFB + col] = acc[x][y][r];
            }
        }
    }
}

__global__ __launch_bounds__(256) void finalize_fallback(
    const float* __restrict__ Cp, const float* __restrict__ b_emb,
    const float* __restrict__ w_act, const float* __restrict__ b_act,
    const float* __restrict__ w_acty, const float* __restrict__ b_acty,
    const int* __restrict__ bboxes_num, float* __restrict__ out, int splitk)
{
    __shared__ __attribute__((aligned(16))) float h[MAXN][NFB];
    __shared__ float pooled[NFB];
    const int bt = blockIdx.x;
    const int t  = threadIdx.x;
    const int Nb = bboxes_num[bt];

    for (int i = 0; i < MAXN; ++i) {
        const int flat = i * 256 + t;
        const int row  = flat >> 8;
        const int f4   = flat & 255;
        const size_t base = ((size_t)(bt * MAXN + row)) * NFB + f4 * 4;
        float4 v = *(const float4*)(Cp + base);
        for (int s2 = 1; s2 < splitk; ++s2) {
            const float4 w = *(const float4*)(Cp + (size_t)s2 * MTOT * NFB + base);
            v.x += w.x; v.y += w.y; v.z += w.z; v.w += w.w;
        }
        const float4 be = *(const float4*)(b_emb + f4 * 4);
        v.x = fmaxf(v.x + be.x, 0.f);
        v.y = fmaxf(v.y + be.y, 0.f);
        v.z = fmaxf(v.z + be.z, 0.f);
        v.w = fmaxf(v.w + be.w, 0.f);
        *(float4*)(&h[row][f4 * 4]) = v;
    }
    __syncthreads();
    const int wave = t >> 6, lane = t & 63;
    for (int d = wave; d < MAXN * NA; d += 4) {
        const int n = d / NA, a = d % NA;
        float sum = 0.f;
        for (int f = lane; f < NFB; f += 64)
            sum += h[n][f] * w_act[f * NA + a];
#pragma unroll
        for (int o = 32; o > 0; o >>= 1) sum += __shfl_xor(sum, o);
        if (lane == 0)
            out[bt * (MAXN * NA) + d] = (n < Nb) ? (sum + b_act[a]) : 0.f;
    }
    for (int f = t; f < NFB; f += 256) {
        float m = h[0][f];
        for (int n2 = 1; n2 < Nb; ++n2) m = fmaxf(m, h[n2][f]);
        pooled[f] = m;
    }
    __syncthreads();
    for (int g = wave; g < NG; g += 4) {
        float sum = 0.f;
        for (int f = lane; f < NFB; f += 64)
            sum += pooled[f] * w_acty[f * NG + g];
#pragma unroll
        for (int o = 32; o > 0; o >>= 1) sum += __shfl_xor(sum, o);
        if (lane == 0)
            out[NBT * MAXN * NA + bt * NG + g] = sum + b_acty[g];
    }
}

extern "C" void kernel_launch(void* const* d_in, const int* in_sizes, int n_in,
                              void* d_out, int out_size, void* d_ws, size_t ws_size,
                              hipStream_t stream) {
    const float* A      = (const float*)d_in[0];
    const float* W      = (const float*)d_in[1];
    const float* b_emb  = (const float*)d_in[2];
    const float* w_act  = (const float*)d_in[3];
    const float* b_act  = (const float*)d_in[4];
    const float* w_acty = (const float*)d_in[5];
    const float* b_acty = (const float*)d_in[6];
    const int*   bboxes = (const int*)d_in[7];
    float* out = (float*)d_out;

    const size_t PACKA = (size_t)AIMG * KITERS * TILEB;   // 67,584,000 B
    const size_t PACKB = (size_t)NT128 * KITERS * TILEB;  // 54,067,200 B
    const size_t PART  = (size_t)MTOT * NFB * 4;          //  4,259,840 B
    const size_t METAB = 8192;

    long avail = (long)ws_size - (long)(PACKA + PACKB + METAB);
    int splitk = (int)(avail / (long)PART);
    if (splitk > 20) splitk = 20;

    if (splitk >= 4) {
        // kchunk: multiple of 3 so the 3-step pipeline divides every chunk
        const int kchunk = ((KITERS + 3 * splitk - 1) / (3 * splitk)) * 3;
        const int nchunks = (KITERS + kchunk - 1) / kchunk;

        unsigned short* Ap = (unsigned short*)d_ws;
        unsigned short* Bp = (unsigned short*)((char*)d_ws + PACKA);
        float* Cp = (float*)((char*)d_ws + PACKA + PACKB);
        int* meta = (int*)((char*)d_ws + PACKA + PACKB + (size_t)splitk * PART);
        float* h  = (float*)d_ws;   // aliases PACKA (dead after gemm)

        prefix_kernel<<<1, 256, 0, stream>>>(bboxes, meta);
        // B blocks first (128 KB each), then A blocks (dead ones exit)
        pack_ab<<<dim3(KITERS + AIMG * ITG), 256, 0, stream>>>(A, W, meta, Ap, Bp);
        // 1-D grid, XCD-group swizzle (see kernel comment); bm-major pair order
        gemm_pipe<<<dim3(NT256 * nchunks * MT256), 512, 0, stream>>>(Ap, Bp, Cp,
                                                                     meta, kchunk);
        reduce_kernel<<<MTOT, 256, 0, stream>>>(Cp, b_emb, h, meta, nchunks);
        heads_kernel<<<NBT, 256, 0, stream>>>(h, w_act, b_act, w_acty, b_acty,
                                              meta, out);
    } else {
        float* Cp = (float*)d_ws;  // needs 17 MB
        gemm_f32<<<dim3(9, 8, 4), 256, 0, stream>>>(A, W, Cp, 207);
        finalize_fallback<<<NBT, 256, 0, stream>>>(Cp, b_emb, w_act, b_act,
                                                   w_acty, b_acty, bboxes, out, 4);
    }
}

// Round 5
// 347.547 us; speedup vs baseline: 1.0194x; 1.0194x over previous
//
#include <hip/hip_runtime.h>

#define K2D 26400
#define NFB 1024
#define NBT 80
#define MAXN 13
#define MTOT (NBT * MAXN)   // 1040
#define NA 6
#define NG 5
#define KITERS 825          // K2D / 32
#define TILEB 8192          // bytes of one packed 128x32 bf16 tile image
#define NT128 8             // B pack images (128 cols each)
#define MT256 5             // GEMM M tiles of 256
#define NT256 4             // GEMM N tiles of 256

typedef __attribute__((ext_vector_type(8))) short     bf16x8;
typedef __attribute__((ext_vector_type(4))) float     f32x4;
typedef __attribute__((ext_vector_type(4))) unsigned short us4;
typedef __attribute__((ext_vector_type(8))) unsigned short us8;

__device__ __forceinline__ unsigned short f2bf(float x) {
    unsigned u = __float_as_uint(x);
    u += 0x7fffu + ((u >> 16) & 1u);
    return (unsigned short)(u >> 16);
}

__device__ __forceinline__ void gload_lds16(const void* g, void* l) {
    __builtin_amdgcn_global_load_lds(
        (const __attribute__((address_space(1))) unsigned int*)g,
        (__attribute__((address_space(3))) unsigned int*)l, 16, 0, 0);
}

// pack two f32x4 -> bf16x8 via HW packed converts (RNE, matches f2bf on normals)
__device__ __forceinline__ bf16x8 cvt8(f32x4 lo, f32x4 hi) {
    unsigned r0, r1, r2, r3;
    asm("v_cvt_pk_bf16_f32 %0, %1, %2" : "=v"(r0) : "v"(lo[0]), "v"(lo[1]));
    asm("v_cvt_pk_bf16_f32 %0, %1, %2" : "=v"(r1) : "v"(lo[2]), "v"(lo[3]));
    asm("v_cvt_pk_bf16_f32 %0, %1, %2" : "=v"(r2) : "v"(hi[0]), "v"(hi[1]));
    asm("v_cvt_pk_bf16_f32 %0, %1, %2" : "=v"(r3) : "v"(hi[2]), "v"(hi[3]));
    union { unsigned u[4]; bf16x8 v; } o;
    o.u[0] = r0; o.u[1] = r1; o.u[2] = r2; o.u[3] = r3;
    return o.v;
}

// meta layout (ints): [0]=total, [1..81]=offsets[0..80], [82..82+1039]=row map
#define META_OFFS 1
#define META_MAP  82

// ---- parallel prefix of box counts + compacted-row -> source-row map
__global__ __launch_bounds__(256) void prefix_kernel(const int* __restrict__ nb,
                                                     int* __restrict__ meta)
{
    __shared__ int a[128];
    const int t = threadIdx.x;
    if (t < 128) a[t] = (t < NBT) ? nb[t] : 0;
    __syncthreads();
#pragma unroll
    for (int s = 1; s < 128; s <<= 1) {       // Hillis-Steele inclusive scan
        int v = 0;
        if (t < 128 && t >= s) v = a[t - s];
        __syncthreads();
        if (t < 128) a[t] += v;
        __syncthreads();
    }
    if (t == 0) { meta[0] = a[NBT - 1]; meta[META_OFFS] = 0; }
    if (t < NBT) meta[META_OFFS + t + 1] = a[t];
    for (int f = t; f < NBT * MAXN; f += 256) {
        const int bt = f / MAXN, n = f % MAXN;
        const int o0 = bt ? a[bt - 1] : 0;
        if (n < a[bt] - o0) meta[META_MAP + o0 + n] = f;
    }
}

// ---- B-only pack (A-pack eliminated; GEMM gathers A directly).
//      One block packs all 8 bn images for one k-iter (R3-proven path).
__global__ __launch_bounds__(256, 4) void pack_b(
    const float* __restrict__ W, unsigned short* __restrict__ Bout)
{
    const int it = blockIdx.x, t = threadIdx.x;
    const float* wbase = W + (size_t)it * 32 * NFB;   // 32 whole rows
    unsigned short* ob = Bout + (size_t)it * (TILEB / 2);
#pragma unroll
    for (int cp = 0; cp < 8; ++cp) {
        const int c0 = (2 * cp) * 256 + t;   // c = bn*512 + q*128 + n
        const int c1 = c0 + 256;
        const int bn0 = c0 >> 9, q0 = (c0 >> 7) & 3, n0 = c0 & 127;
        const int bn1 = c1 >> 9, q1 = (c1 >> 7) & 3, n1 = c1 & 127;
        const float* bp0 = wbase + (size_t)(q0 * 8) * NFB + bn0 * 128 + n0;
        const float* bp1 = wbase + (size_t)(q1 * 8) * NFB + bn1 * 128 + n1;
        float v0[8], v1[8];
#pragma unroll
        for (int j = 0; j < 8; ++j) v0[j] = bp0[(size_t)j * NFB];
#pragma unroll
        for (int j = 0; j < 8; ++j) v1[j] = bp1[(size_t)j * NFB];
        us8 u0, u1;
#pragma unroll
        for (int j = 0; j < 8; ++j) u0[j] = f2bf(v0[j]);
#pragma unroll
        for (int j = 0; j < 8; ++j) u1[j] = f2bf(v1[j]);
        *(us8*)(ob + (size_t)bn0 * KITERS * (TILEB / 2) + (q0 * 128 + n0) * 8) = u0;
        *(us8*)(ob + (size_t)bn1 * KITERS * (TILEB / 2) + (q1 * 128 + n1) * 8) = u1;
    }
}

// ---- pipelined 256x256 GEMM v2: A gathered DIRECTLY from f32 input.
//      Per stage (48 KB x 3 = 144 KB LDS; 160 KB is the gfx950 workgroup max):
//        [0,32K):  A f32 tile [256 rows][128 B], k-seg XOR-swizzled by row&7
//                  (swizzle applied on the per-lane GLOBAL source; LDS linear)
//        [32K..):  2 packed-B bf16 images (8 KB each), layout as pack_b emits
//      ISSUE = 4 A-gloads + 2 B-gloads per wave -> s_waitcnt vmcnt(6)/step.
//      af frags: 2 swizzled ds_read_b128 (f32) + 4 v_cvt_pk_bf16_f32.
//      XCD-group swizzle on blockIdx unchanged (4 bn share A stripe on one L2).
__global__ __launch_bounds__(512, 2) void gemm_pipe(
    const float* __restrict__ A,
    const unsigned short* __restrict__ Bpack,
    float* __restrict__ Cp,
    const int* __restrict__ meta, int kchunk)
{
    __shared__ __attribute__((aligned(16))) char smem[3][49152]; // 144 KB

    const int id     = (int)blockIdx.x;
    const int npairs = (int)(gridDim.x >> 2);        // MT256 * nchunks
    const int nmain  = npairs & ~7;
    int pair, bn;
    if (id < (nmain << 2)) { pair = ((id >> 5) << 3) + (id & 7); bn = (id >> 3) & 3; }
    else { const int r = id - (nmain << 2); pair = nmain + (r >> 2); bn = r & 3; }
    const int nch = npairs / MT256;
    const int bm  = pair / nch;                      // bm-major: active first
    const int s   = pair % nch;

    const int total = meta[0];
    if (bm * 256 >= total) return;

    const int t = threadIdx.x;
    const int wave = t >> 6, lane = t & 63;
    const int quad = lane >> 4, l16 = lane & 15;
    const int wmq = wave & 3;            // row quadrant (64 rows each)
    const int bsel = wave >> 2;          // B image 0/1 (128 cols each)
    const int it0 = s * kchunk;
    const int it1 = min(KITERS, it0 + kchunk);   // kchunk%3==0, 825%3==0

    // per-lane A gather bases: 4 row-groups of 8 rows; source pre-swizzled
    // so linear LDS slot (l&7) holds global k-seg (l&7)^(row&7).
    const float* baseA[4];
#pragma unroll
    for (int j = 0; j < 4; ++j) {
        const int R = wave * 32 + j * 8 + (lane >> 3);   // local tile row
        const int p = bm * 256 + R;                      // compacted row
        const int src = (p < total) ? meta[META_MAP + p] : 0;
        const int segsw = (lane & 7) ^ ((lane >> 3) & 7);
        baseA[j] = A + (size_t)src * K2D + segsw * 4;
    }

    f32x4 acc[4][8] = {};

    {
        const int itlast = it1 - 1;
        const char* B0 = (const char*)Bpack + (size_t)(2 * bn) * KITERS * TILEB;
        const char* B1 = (const char*)Bpack + (size_t)(2 * bn + 1) * KITERS * TILEB;

#define ISSUE(IT, ST) do {                                                     \
    char* sa = &smem[ST][0] + wave * 4096;                                     \
    _Pragma("unroll")                                                          \
    for (int j = 0; j < 4; ++j)                                                \
        gload_lds16(baseA[j] + (size_t)(IT) * 32, sa + j * 1024);              \
    gload_lds16(B0 + (size_t)(IT) * TILEB + t * 16,                            \
                &smem[ST][32768] + wave * 1024);                               \
    gload_lds16(B1 + (size_t)(IT) * TILEB + t * 16,                            \
                &smem[ST][40960] + wave * 1024);                               \
} while (0)

        ISSUE(it0, 0);
        { const int itp = min(it0 + 1, itlast); ISSUE(itp, 1); }

#define STEP(ITV, CUR, DST) do {                                               \
    asm volatile("" ::: "memory");                                             \
    __builtin_amdgcn_s_waitcnt(0xF76); /* vmcnt(6) */                          \
    __builtin_amdgcn_s_barrier();                                              \
    asm volatile("" ::: "memory");                                             \
    int itn = (ITV) + 2; itn = itn > itlast ? itlast : itn;                    \
    ISSUE(itn, DST);                                                           \
    bf16x8 af[4], bfr[8];                                                      \
    _Pragma("unroll")                                                          \
    for (int x = 0; x < 4; ++x) {                                              \
        const int R = wmq * 64 + x * 16 + l16;                                 \
        const char* ra = &smem[CUR][0] + R * 128;                              \
        const int sw = l16 & 7;                                                \
        f32x4 lo = *(const f32x4*)(ra + (((2 * quad)     ^ sw) * 16));         \
        f32x4 hi = *(const f32x4*)(ra + (((2 * quad + 1) ^ sw) * 16));         \
        af[x] = cvt8(lo, hi);                                                  \
    }                                                                          \
    _Pragma("unroll")                                                          \
    for (int y = 0; y < 8; ++y)                                                \
        bfr[y] = *(const bf16x8*)(&smem[CUR][32768] + bsel * 8192              \
                                  + quad * 2048 + (y * 16 + l16) * 16);        \
    _Pragma("unroll")                                                          \
    for (int x = 0; x < 4; ++x)                                                \
        _Pragma("unroll")                                                      \
        for (int y = 0; y < 8; ++y)                                            \
            acc[x][y] = __builtin_amdgcn_mfma_f32_16x16x32_bf16(               \
                af[x], bfr[y], acc[x][y], 0, 0, 0);                            \
} while (0)

        for (int it = it0; it < it1; it += 3) {
            STEP(it,     0, 2);
            STEP(it + 1, 1, 0);
            STEP(it + 2, 2, 1);
        }
#undef STEP
#undef ISSUE
    }

    // C write; rows >= total are garbage but never read downstream.
#pragma unroll
    for (int x = 0; x < 4; ++x) {
        const int rowb = bm * 256 + wmq * 64 + x * 16 + quad * 4;
#pragma unroll
        for (int y = 0; y < 8; ++y) {
            const int col = bn * 256 + bsel * 128 + y * 16 + l16;
#pragma unroll
            for (int r = 0; r < 4; ++r) {
                const int rr = rowb + r;
                if (rr < MTOT)
                    Cp[((size_t)s * MTOT + rr) * NFB + col] = acc[x][y][r];
            }
        }
    }
}

// ---- parallel split-K reduce: one block per compacted row
__global__ __launch_bounds__(256) void reduce_kernel(
    const float* __restrict__ Cp, const float* __restrict__ b_emb,
    float* __restrict__ h, const int* __restrict__ meta, int splitk)
{
    const int row = blockIdx.x;
    if (row >= meta[0]) return;
    const int t = threadIdx.x;
    const size_t base = (size_t)row * NFB + t * 4;
    float4 v = *(const float4*)(Cp + base);
#pragma unroll 4
    for (int s2 = 1; s2 < splitk; ++s2) {
        const float4 w = *(const float4*)(Cp + (size_t)s2 * MTOT * NFB + base);
        v.x += w.x; v.y += w.y; v.z += w.z; v.w += w.w;
    }
    const float4 be = *(const float4*)(b_emb + t * 4);
    v.x = fmaxf(v.x + be.x, 0.f);
    v.y = fmaxf(v.y + be.y, 0.f);
    v.z = fmaxf(v.z + be.z, 0.f);
    v.w = fmaxf(v.w + be.w, 0.f);
    *(float4*)(h + base) = v;
}

// ---- per-frame heads on compacted h
__global__ __launch_bounds__(256) void heads_kernel(
    const float* __restrict__ h,
    const float* __restrict__ w_act,  const float* __restrict__ b_act,
    const float* __restrict__ w_acty, const float* __restrict__ b_acty,
    const int* __restrict__ meta, float* __restrict__ out)
{
    __shared__ __attribute__((aligned(16))) float hs[MAXN][NFB];
    __shared__ float pooled[NFB];
    const int bt = blockIdx.x;
    const int t  = threadIdx.x;
    const int off0 = meta[META_OFFS + bt];
    const int Nb   = meta[META_OFFS + bt + 1] - off0;

    for (int i = 0; i < MAXN; ++i)
        if (i < Nb)
            *(float4*)(&hs[i][t * 4]) =
                *(const float4*)(h + (size_t)(off0 + i) * NFB + t * 4);
    __syncthreads();

    const int wave = t >> 6, lane = t & 63;

    for (int d = wave; d < MAXN * NA; d += 4) {
        const int n = d / NA, a = d % NA;
        if (n < Nb) {
            float sum = 0.f;
            for (int f = lane; f < NFB; f += 64)
                sum += hs[n][f] * w_act[f * NA + a];
#pragma unroll
            for (int o = 32; o > 0; o >>= 1) sum += __shfl_xor(sum, o);
            if (lane == 0) out[bt * (MAXN * NA) + d] = sum + b_act[a];
        } else {
            if (lane == 0) out[bt * (MAXN * NA) + d] = 0.f;
        }
    }

    for (int f = t; f < NFB; f += 256) {
        float m = hs[0][f];
        for (int n2 = 1; n2 < Nb; ++n2) m = fmaxf(m, hs[n2][f]);
        pooled[f] = m;
    }
    __syncthreads();

    for (int g = wave; g < NG; g += 4) {
        float sum = 0.f;
        for (int f = lane; f < NFB; f += 64)
            sum += pooled[f] * w_acty[f * NG + g];
#pragma unroll
        for (int o = 32; o > 0; o >>= 1) sum += __shfl_xor(sum, o);
        if (lane == 0)
            out[NBT * MAXN * NA + bt * NG + g] = sum + b_acty[g];
    }
}

// ======== fallback path (round-1 proven), used only if ws too small ========
__global__ __launch_bounds__(256) void gemm_f32(
    const float* __restrict__ A, const float* __restrict__ B,
    float* __restrict__ Cp, int kchunk)
{
    __shared__ __attribute__((aligned(16))) unsigned short Alds[4][128][8];
    __shared__ __attribute__((aligned(16))) unsigned short Blds[4][128][8];
    const int t = threadIdx.x;
    const int bm = blockIdx.x, bn = blockIdx.y, s = blockIdx.z;
    const int wave = t >> 6, lane = t & 63;
    const int quad = lane >> 4, l16 = lane & 15;
    const int wm = (wave & 1) * 64, wn = (wave >> 1) * 64;
    const int row0 = bm * 128, col0 = bn * 128;
    const int it0 = s * kchunk, it1 = min(KITERS, it0 + kchunk);

    f32x4 acc[4][4] = {};
    for (int it = it0; it < it1; ++it) {
        const int k0 = it * 32;
#pragma unroll
        for (int i = 0; i < 4; ++i) {
            const int f = t + i * 256, m = f >> 3, kp = (f & 7) * 4;
            const int gr = row0 + m;
            float4 v = {0.f, 0.f, 0.f, 0.f};
            if (gr < MTOT) v = *(const float4*)(A + (size_t)gr * K2D + k0 + kp);
            us4 u = { f2bf(v.x), f2bf(v.y), f2bf(v.z), f2bf(v.w) };
            *(us4*)(&Alds[kp >> 3][m][kp & 7]) = u;
        }
#pragma unroll
        for (int i = 0; i < 2; ++i) {
            const int p = t + i * 256, n = p & 127, kq = p >> 7;
            const float* bp = B + (size_t)(k0 + kq * 8) * NFB + (col0 + n);
            us8 u;
#pragma unroll
            for (int j = 0; j < 8; ++j) u[j] = f2bf(bp[(size_t)j * NFB]);
            *(us8*)(&Blds[kq][n][0]) = u;
        }
        __syncthreads();
        bf16x8 af[4], bfr[4];
#pragma unroll
        for (int x = 0; x < 4; ++x) {
            af[x]  = *(const bf16x8*)(&Alds[quad][wm + x * 16 + l16][0]);
            bfr[x] = *(const bf16x8*)(&Blds[quad][wn + x * 16 + l16][0]);
        }
#pragma unroll
        for (int x = 0; x < 4; ++x)
#pragma unroll
            for (int y = 0; y < 4; ++y)
                acc[x][y] = __builtin_amdgcn_mfma_f32_16x16x32_bf16(
                    af[x], bfr[y], acc[x][y], 0, 0, 0);
        __syncthreads();
    }
#pragma unroll
    for (int x = 0; x < 4; ++x) {
        const int rowb = row0 + wm + x * 16 + quad * 4;
#pragma unroll
        for (int y = 0; y < 4; ++y) {
            const int col = col0 + wn + y * 16 + l16;
#pragma unroll
            for (int r = 0; r < 4; ++r) {
                const int rr = rowb + r;
                if (rr < MTOT)
                    Cp[((size_t)s * MTOT + rr) * NFB + col] = acc[x][y][r];
            }
        }
    }
}

__global__ __launch_bounds__(256) void finalize_fallback(
    const float* __restrict__ Cp, const float* __restrict__ b_emb,
    const float* __restrict__ w_act, const float* __restrict__ b_act,
    const float* __restrict__ w_acty, const float* __restrict__ b_acty,
    const int* __restrict__ bboxes_num, float* __restrict__ out, int splitk)
{
    __shared__ __attribute__((aligned(16))) float h[MAXN][NFB];
    __shared__ float pooled[NFB];
    const int bt = blockIdx.x;
    const int t  = threadIdx.x;
    const int Nb = bboxes_num[bt];

    for (int i = 0; i < MAXN; ++i) {
        const int flat = i * 256 + t;
        const int row  = flat >> 8;
        const int f4   = flat & 255;
        const size_t base = ((size_t)(bt * MAXN + row)) * NFB + f4 * 4;
        float4 v = *(const float4*)(Cp + base);
        for (int s2 = 1; s2 < splitk; ++s2) {
            const float4 w = *(const float4*)(Cp + (size_t)s2 * MTOT * NFB + base);
            v.x += w.x; v.y += w.y; v.z += w.z; v.w += w.w;
        }
        const float4 be = *(const float4*)(b_emb + f4 * 4);
        v.x = fmaxf(v.x + be.x, 0.f);
        v.y = fmaxf(v.y + be.y, 0.f);
        v.z = fmaxf(v.z + be.z, 0.f);
        v.w = fmaxf(v.w + be.w, 0.f);
        *(float4*)(&h[row][f4 * 4]) = v;
    }
    __syncthreads();
    const int wave = t >> 6, lane = t & 63;
    for (int d = wave; d < MAXN * NA; d += 4) {
        const int n = d / NA, a = d % NA;
        float sum = 0.f;
        for (int f = lane; f < NFB; f += 64)
            sum += h[n][f] * w_act[f * NA + a];
#pragma unroll
        for (int o = 32; o > 0; o >>= 1) sum += __shfl_xor(sum, o);
        if (lane == 0)
            out[bt * (MAXN * NA) + d] = (n < Nb) ? (sum + b_act[a]) : 0.f;
    }
    for (int f = t; f < NFB; f += 256) {
        float m = h[0][f];
        for (int n2 = 1; n2 < Nb; ++n2) m = fmaxf(m, h[n2][f]);
        pooled[f] = m;
    }
    __syncthreads();
    for (int g = wave; g < NG; g += 4) {
        float sum = 0.f;
        for (int f = lane; f < NFB; f += 64)
            sum += pooled[f] * w_acty[f * NG + g];
#pragma unroll
        for (int o = 32; o > 0; o >>= 1) sum += __shfl_xor(sum, o);
        if (lane == 0)
            out[NBT * MAXN * NA + bt * NG + g] = sum + b_acty[g];
    }
}

extern "C" void kernel_launch(void* const* d_in, const int* in_sizes, int n_in,
                              void* d_out, int out_size, void* d_ws, size_t ws_size,
                              hipStream_t stream) {
    const float* A      = (const float*)d_in[0];
    const float* W      = (const float*)d_in[1];
    const float* b_emb  = (const float*)d_in[2];
    const float* w_act  = (const float*)d_in[3];
    const float* b_act  = (const float*)d_in[4];
    const float* w_acty = (const float*)d_in[5];
    const float* b_acty = (const float*)d_in[6];
    const int*   bboxes = (const int*)d_in[7];
    float* out = (float*)d_out;

    const size_t PACKB = (size_t)NT128 * KITERS * TILEB;  // 54,067,200 B
    const size_t PART  = (size_t)MTOT * NFB * 4;          //  4,259,840 B
    const size_t METAB = 8192;

    long avail = (long)ws_size - (long)(PACKB + METAB);
    int splitk = (int)(avail / (long)PART);
    if (splitk > 20) splitk = 20;

    if (splitk >= 4) {
        // kchunk: multiple of 3 so the 3-step pipeline divides every chunk
        const int kchunk = ((KITERS + 3 * splitk - 1) / (3 * splitk)) * 3;
        const int nchunks = (KITERS + kchunk - 1) / kchunk;

        unsigned short* Bp = (unsigned short*)d_ws;
        float* Cp = (float*)((char*)d_ws + PACKB);
        int* meta = (int*)((char*)d_ws + PACKB + (size_t)splitk * PART);
        float* h  = (float*)d_ws;   // aliases PACKB (dead after gemm)

        prefix_kernel<<<1, 256, 0, stream>>>(bboxes, meta);
        pack_b<<<dim3(KITERS), 256, 0, stream>>>(W, Bp);
        gemm_pipe<<<dim3(NT256 * nchunks * MT256), 512, 0, stream>>>(A, Bp, Cp,
                                                                     meta, kchunk);
        reduce_kernel<<<MTOT, 256, 0, stream>>>(Cp, b_emb, h, meta, nchunks);
        heads_kernel<<<NBT, 256, 0, stream>>>(h, w_act, b_act, w_acty, b_acty,
                                              meta, out);
    } else {
        float* Cp = (float*)d_ws;  // needs 17 MB
        gemm_f32<<<dim3(9, 8, 4), 256, 0, stream>>>(A, W, Cp, 207);
        finalize_fallback<<<NBT, 256, 0, stream>>>(Cp, b_emb, w_act, b_act,
                                                   w_acty, b_acty, bboxes, out, 4);
    }
}